// Round 7
// baseline (245.528 us; speedup 1.0000x reference)
//
#include <hip/hip_runtime.h>
#include <hip/hip_bf16.h>
#include <stdint.h>

typedef __attribute__((ext_vector_type(8))) short short8;  // 8 bf16 (4 VGPRs)
typedef __attribute__((ext_vector_type(4))) float f32x4;   // 4 fp32 acc

__device__ __forceinline__ uint16_t f2bf(float f) {
    union { float f; uint32_t u; } v; v.f = f;
    uint32_t r = v.u + 0x7FFF + ((v.u >> 16) & 1);  // RNE
    return (uint16_t)(r >> 16);
}
__device__ __forceinline__ float bf2f(uint16_t u) {
    union { uint32_t u; float f; } v; v.u = ((uint32_t)u) << 16;
    return v.f;
}
__device__ __forceinline__ float exp2_raw(float x) {
    float r;
    asm("v_exp_f32 %0, %1" : "=v"(r) : "v"(x));
    return r;
}
__device__ __forceinline__ uint32_t cvt_pk_bf16(float lo, float hi) {
    uint32_t r;
    asm("v_cvt_pk_bf16_f32 %0, %1, %2" : "=v"(r) : "v"(lo), "v"(hi));
    return r;
}

template<int F32>
__device__ __forceinline__ uint4 load8(const void* p, size_t off) {
    if (F32) {
        const float* f = (const float*)p + off;
        float4 f0 = *(const float4*)f;
        float4 f1 = *(const float4*)(f + 4);
        uint4 r;
        r.x = (uint32_t)f2bf(f0.x) | ((uint32_t)f2bf(f0.y) << 16);
        r.y = (uint32_t)f2bf(f0.z) | ((uint32_t)f2bf(f0.w) << 16);
        r.z = (uint32_t)f2bf(f1.x) | ((uint32_t)f2bf(f1.y) << 16);
        r.w = (uint32_t)f2bf(f1.z) | ((uint32_t)f2bf(f1.w) << 16);
        return r;
    } else {
        return *(const uint4*)((const uint16_t*)p + off);
    }
}

// global -> LDS direct DMA, 16 B/lane; LDS dest = wave-uniform base + lane*16.
#define GLDS(gp, lp) __builtin_amdgcn_global_load_lds( \
    (const __attribute__((address_space(1))) void*)(gp), \
    (__attribute__((address_space(3))) void*)(lp), 16, 0, 0)

// ---------------------------------------------------------------------------
// cvt (x + weights + pos) + mask canonicalization fused. Mask products:
//  * mbits: 1024-bit-per-batch bitmask (used by gemm128_qkv V-epilogue)
//  * mvals: bf16 {1.0 unmasked, 0.0 masked} per (b,k) — flash_attn's
//    denominator B-fragment (lsum via MFMA instead of 64 VALU adds/iter).
// ---------------------------------------------------------------------------
struct CvtSeg { const float* s; uint16_t* d; int n8; };
struct CvtArgs {
    CvtSeg seg[9]; int nseg;
    const void* mraw; unsigned long long* mbits; uint16_t* mvals;
};

__global__ __launch_bounds__(256) void cvt_bf16(CvtArgs a)
{
    if (blockIdx.x == 0) {
        __shared__ int flags[3];
        __shared__ uint8_t mloc[4096];
        const uint32_t* w = (const uint32_t*)a.mraw;
        const uint8_t* b8 = (const uint8_t*)a.mraw;
        const int t = threadIdx.x;
        if (t < 3) flags[t] = 0;
        __syncthreads();
        int fbyte = 0, ff32 = 0, fodd = 0;
        for (int i = t; i < 1024; i += 256) {
            uint32_t v = w[i];
            if (v != 0u && v != 1u && v != 0x3F800000u) fbyte = 1;
            if (v == 0x3F800000u) ff32 = 1;
            if ((i & 1) && v != 0u) fodd = 1;
        }
        if (fbyte) atomicOr(&flags[0], 1);
        if (ff32)  atomicOr(&flags[1], 1);
        if (fodd)  atomicOr(&flags[2], 1);
        __syncthreads();
        int mode;  // 0 = word, 1 = byte, 2 = int64
        if (flags[0]) mode = 1;
        else if (flags[1]) mode = 0;
        else if (!flags[2]) mode = 2;
        else mode = 0;
        for (int k = t; k < 4096; k += 256) {
            int val;
            if (mode == 1)      val = (b8[k] != 0);
            else if (mode == 2) val = (w[2 * k] != 0u);
            else                val = (w[k] != 0u);
            mloc[k] = (uint8_t)val;
        }
        __syncthreads();
        for (int k = t; k < 4096; k += 256)
            a.mvals[k] = mloc[k] ? (uint16_t)0 : (uint16_t)0x3F80;
        if (t < 64) {
            uint64_t bits = 0;
#pragma unroll
            for (int i = 0; i < 64; ++i)
                bits |= (uint64_t)mloc[t * 64 + i] << i;
            a.mbits[t] = bits;
        }
    }
    const int tid = blockIdx.x * 256 + threadIdx.x;
    const int stride = gridDim.x * 256;
    for (int s = 0; s < a.nseg; ++s) {
        const float* src = a.seg[s].s;
        uint16_t* dst = a.seg[s].d;
        const int n8 = a.seg[s].n8;
        if (src) {
            for (int i = tid; i < n8; i += stride)
                *(uint4*)(dst + (size_t)i * 8) = load8<1>(src, (size_t)i * 8);
        } else {
            const uint4 z = {0u, 0u, 0u, 0u};
            for (int i = tid; i < n8; i += stride)
                *(uint4*)(dst + (size_t)i * 8) = z;
        }
    }
}

// ---------------------------------------------------------------------------
// QKV GEMM, 128x128 tile, BK=64 — r13-proven main loop, untouched.
// K (z==1) and V (z==2) written in MFMA-FRAGMENT order so flash_attn's
// per-lane loads are fully coalesced (lane*16B within a 512-u16 = 1KB slot).
// r6 BUG (fixed): slot = 64 lanes x 8 u16 = 512 u16 (1KB), NOT 1024; tile =
// 8 slots = 4096 u16, NOT 8192 — the 2x strides overran each bh's 65536-u16
// region and clobbered the next head (absmax 0.134). 16 tiles x 4096 = 65536 ✓.
// Layout per bh (65536 u16):
//   K: addr = (key>>6)*4096 + (((key>>4)&3)*2 + (d>>5))*512
//           + ((d>>3)&3)*128 + (key&15)*8 + (d&7)
//   V: addr = (key>>6)*4096 + ((d>>4)*2 + ((key>>5)&1))*512
//           + ((key>>3)&3)*128 + (d&15)*8 + (key&7)
// Store counts unchanged vs r5 (r4 lesson: no new loads in store paths).
// V epilogue still zeroes masked key columns (wave-uniform s_load of mbits).
// ---------------------------------------------------------------------------
__global__ __launch_bounds__(256) void gemm128_qkv(
    const uint16_t* __restrict__ xq, const uint16_t* __restrict__ xk, const uint16_t* __restrict__ xv,
    const uint16_t* __restrict__ Wq, const uint16_t* __restrict__ Wk, const uint16_t* __restrict__ Wv,
    uint16_t* __restrict__ Qh, uint16_t* __restrict__ Khd, uint16_t* __restrict__ Vt,
    const unsigned long long* __restrict__ mbits)
{
    __shared__ alignas(16) uint16_t As[2][128 * 32];   // k-halves
    __shared__ alignas(16) uint16_t Bs[2][128 * 32];

    const int z = blockIdx.z;
    const uint16_t* A = (z == 0) ? xq : (z == 1) ? xk : xv;
    const uint16_t* B = (z == 0) ? Wq : (z == 1) ? Wk : Wv;
    uint16_t* C = (z == 0) ? Qh : (z == 1) ? Khd : Vt;
    const int cm = (z == 2) ? 2 : 1;
    const int bm = blockIdx.x, bn = blockIdx.y;
    const int K = 1024;

    const int t = threadIdx.x;
    const int lane = t & 63, wave = t >> 6;
    const int lrow = lane & 15, quad = lane >> 4;
    const int wr = (wave >> 1) * 64, wc = (wave & 1) * 64;
    const int g_row = wave * 16 + (lane >> 2);
    const int g_col = (lane & 3) * 8;

    const f32x4 fz = {0.f, 0.f, 0.f, 0.f};
    f32x4 acc[4][4];
#pragma unroll
    for (int i = 0; i < 4; ++i)
#pragma unroll
        for (int j = 0; j < 4; ++j) acc[i][j] = fz;

    for (int k0 = 0; k0 < K; k0 += 64) {
        __syncthreads();
#pragma unroll
        for (int kh = 0; kh < 2; ++kh) {
            const int kk = k0 + kh * 32;
            GLDS(A + (size_t)(bm * 128 + g_row) * K + kk + g_col,      As[kh] + wave * 512);
            GLDS(A + (size_t)(bm * 128 + g_row + 64) * K + kk + g_col, As[kh] + wave * 512 + 2048);
            GLDS(B + (size_t)(bn * 128 + g_row) * K + kk + g_col,      Bs[kh] + wave * 512);
            GLDS(B + (size_t)(bn * 128 + g_row + 64) * K + kk + g_col, Bs[kh] + wave * 512 + 2048);
        }
        __syncthreads();

#pragma unroll
        for (int kh = 0; kh < 2; ++kh) {
            short8 a[4], b[4];
#pragma unroll
            for (int i = 0; i < 4; ++i)
                a[i] = *(const short8*)(As[kh] + (wr + i * 16 + lrow) * 32 + quad * 8);
#pragma unroll
            for (int j = 0; j < 4; ++j)
                b[j] = *(const short8*)(Bs[kh] + (wc + j * 16 + lrow) * 32 + quad * 8);
#pragma unroll
            for (int i = 0; i < 4; ++i)
#pragma unroll
                for (int j = 0; j < 4; ++j)
                    acc[i][j] = __builtin_amdgcn_mfma_f32_16x16x32_bf16(a[i], b[j], acc[i][j], 0, 0, 0);
        }
    }

    if (cm == 2) {
        __syncthreads();
        uint16_t* scr = As[0] + wave * 1024;
        // wave-uniform mask word (r5-proven): one s_load, VALU-extract.
        const int mg0 = bm * 128 + wr;
        const int widx = __builtin_amdgcn_readfirstlane((mg0 >> 10) * 16 + ((mg0 & 1023) >> 6));
        const uint64_t mword = mbits[widx];
        const uint64_t mw64 = mword >> ((lane & 1) * 8);
#pragma unroll
        for (int i = 0; i < 4; ++i)
#pragma unroll
            for (int j = 0; j < 4; ++j) {
                uint2 pk;
                pk.x = (uint32_t)f2bf(acc[i][j][0]) | ((uint32_t)f2bf(acc[i][j][1]) << 16);
                pk.y = (uint32_t)f2bf(acc[i][j][2]) | ((uint32_t)f2bf(acc[i][j][3]) << 16);
                *(uint2*)(scr + lrow * 16 + quad * 4) = pk;
                if (lane < 32) {
                    int n = lane >> 1, m8 = (lane & 1) * 8;
                    short8 vv = *(const short8*)(scr + n * 16 + m8);
                    int ng = bn * 128 + wc + j * 16 + n;        // (h,d)
                    int hh = ng >> 6, d = ng & 63;
                    int mg = bm * 128 + wr + i * 16;            // t base
                    int bb = mg >> 10, tl = (mg & 1023) + m8;   // key base (8-aligned)
                    uint32_t eb = (uint32_t)(mw64 >> (i * 16)) & 0xFFu;
                    if (eb) {
                        union { short8 s; uint32_t u[4]; } uw;
                        uw.s = vv;
#pragma unroll
                        for (int c = 0; c < 4; ++c) {
                            uint32_t km = (((eb >> (2 * c)) & 1) ? 0u : 0x0000FFFFu)
                                        | (((eb >> (2 * c + 1)) & 1) ? 0u : 0xFFFF0000u);
                            uw.u[c] &= km;
                        }
                        vv = uw.s;
                    }
                    // V frag-native addr (keys tl..tl+7 contiguous: e = key&7)
                    size_t addr = (size_t)(bb * 16 + hh) * 65536
                                + (size_t)((tl >> 6) * 4096
                                           + ((d >> 4) * 2 + ((tl >> 5) & 1)) * 512
                                           + ((tl >> 3) & 3) * 128 + (d & 15) * 8);
                    *(short8*)(C + addr) = vv;
                }
            }
        return;
    }

#pragma unroll
    for (int i = 0; i < 4; ++i)
#pragma unroll
        for (int j = 0; j < 4; ++j)
#pragma unroll
            for (int r = 0; r < 4; ++r) {
                // verified C/D map: row = quad*4 + reg, col = lane&15
                int m = bm * 128 + wr + i * 16 + quad * 4 + r;
                int n = bn * 128 + wc + j * 16 + lrow;
                int bb = m >> 10, key = m & 1023, hh = n >> 6, d = n & 63;
                if (z == 0) {
                    C[(((size_t)bb * 16 + hh) * 1024 + key) * 64 + d] = f2bf(acc[i][j][r]);
                } else {
                    // K frag-native addr
                    size_t addr = (size_t)(bb * 16 + hh) * 65536
                                + (size_t)((key >> 6) * 4096
                                           + (((key >> 4) & 3) * 2 + (d >> 5)) * 512
                                           + ((d >> 3) & 3) * 128 + (key & 15) * 8 + (d & 7));
                    C[addr] = f2bf(acc[i][j][r]);
                }
            }
}

// ---------------------------------------------------------------------------
// Output projection, 64x128 tiles (512 blocks = 2/CU), BK=64 — exact r13
// version. 16 MFMA/iter. LDS 24KB.
// ---------------------------------------------------------------------------
__global__ __launch_bounds__(256) void gemm_out(
    const uint16_t* __restrict__ A, const uint16_t* __restrict__ B,
    float* __restrict__ C, int M, int N, int K)
{
    __shared__ alignas(16) uint16_t As[2][64 * 32];
    __shared__ alignas(16) uint16_t Bs[2][128 * 32];

    const int t = threadIdx.x;
    const int lane = t & 63, wave = t >> 6;
    const int lrow = lane & 15, quad = lane >> 4;
    const int wr = (wave >> 1) * 32, wc = (wave & 1) * 64;
    const int g_row = wave * 16 + (lane >> 2);
    const int g_col = (lane & 3) * 8;
    const int bm = blockIdx.x, bn = blockIdx.y;

    const f32x4 fz = {0.f, 0.f, 0.f, 0.f};
    f32x4 acc[2][4];
#pragma unroll
    for (int i = 0; i < 2; ++i)
#pragma unroll
        for (int j = 0; j < 4; ++j) acc[i][j] = fz;

    for (int k0 = 0; k0 < K; k0 += 64) {
        __syncthreads();
#pragma unroll
        for (int kh = 0; kh < 2; ++kh) {
            const int kk = k0 + kh * 32;
            GLDS(A + (size_t)(bm * 64 + g_row) * K + kk + g_col,       As[kh] + wave * 512);
            GLDS(B + (size_t)(bn * 128 + g_row) * K + kk + g_col,      Bs[kh] + wave * 512);
            GLDS(B + (size_t)(bn * 128 + g_row + 64) * K + kk + g_col, Bs[kh] + wave * 512 + 2048);
        }
        __syncthreads();

#pragma unroll
        for (int kh = 0; kh < 2; ++kh) {
            short8 a[2], b[4];
#pragma unroll
            for (int i = 0; i < 2; ++i)
                a[i] = *(const short8*)(As[kh] + (wr + i * 16 + lrow) * 32 + quad * 8);
#pragma unroll
            for (int j = 0; j < 4; ++j)
                b[j] = *(const short8*)(Bs[kh] + (wc + j * 16 + lrow) * 32 + quad * 8);
#pragma unroll
            for (int i = 0; i < 2; ++i)
#pragma unroll
                for (int j = 0; j < 4; ++j)
                    acc[i][j] = __builtin_amdgcn_mfma_f32_16x16x32_bf16(a[i], b[j], acc[i][j], 0, 0, 0);
        }
    }

#pragma unroll
    for (int i = 0; i < 2; ++i)
#pragma unroll
        for (int j = 0; j < 4; ++j)
#pragma unroll
            for (int r = 0; r < 4; ++r) {
                int m = bm * 64 + wr + i * 16 + quad * 4 + r;
                int n = bn * 128 + wc + j * 16 + lrow;
                C[(size_t)m * N + n] = acc[i][j][r];
            }
}

// ---------------------------------------------------------------------------
// Flash attention v13b — occupancy play (r6 structure, stride bug fixed).
// r3 failed: uncoalesced direct loads. r6 failed: slot/tile strides 2x too
// big (bytes-vs-elements) -> cross-head clobber. Now:
//  * K/V frag-native: slot = 512 u16 (1KB), tile = 4096 u16; every load is
//    lane*16B within a slot = one fully-coalesced 1KB transaction.
//  * No Ks/Vs/maskl LDS, no GLDS, no __syncthreads (Qpos slab + Pl are
//    wave-private). LDS 79.9K -> 44.7K -> 3 blocks/CU = 3 waves/SIMD.
//  * K + mask prefetched one tile ahead in regs (2-body unroll, static
//    indexing, rule-20 safe); V loaded at tile top, consumed after SM.
// Kept from r5: mask-free SM (V pre-zeroed), MFMA denominator lacc, exp2+CS
// prescale, cvt_pk packing, Qpos width 277, setprio around MFMA clusters.
// LDS: Qpos_l 35456 + Pl 9216 = 44672 B.
// ---------------------------------------------------------------------------
#define FA_SM(KB_)                                                              \
{                                                                               \
    const int diff = (KB_) - qb;                                                \
    if (diff <= -192 || diff >= 144) {                                          \
        const bool low = (diff <= -192);                                        \
        _Pragma("unroll")                                                       \
        for (int j = 0; j < 4; ++j) {                                           \
            float e[4];                                                         \
            _Pragma("unroll")                                                   \
            for (int r = 0; r < 4; ++r) {                                       \
                float pc = low ? pcl[r] : pch[r];                               \
                e[r] = exp2_raw(__builtin_fmaf(s[j][r], CS, pc));               \
            }                                                                   \
            const uint32_t p01 = cvt_pk_bf16(e[0], e[1]);                       \
            const uint32_t p23 = cvt_pk_bf16(e[2], e[3]);                       \
            const int col = j * 16 + lrow;                                      \
            const int rw = quad * 4;                                            \
            Pl[wave][rw + 0][col] = (uint16_t)p01;                              \
            Pl[wave][rw + 1][col] = (uint16_t)(p01 >> 16);                      \
            Pl[wave][rw + 2][col] = (uint16_t)p23;                              \
            Pl[wave][rw + 3][col] = (uint16_t)(p23 >> 16);                      \
        }                                                                       \
    } else {                                                                    \
        _Pragma("unroll")                                                       \
        for (int j = 0; j < 4; ++j) {                                           \
            const int key = (KB_) + j * 16 + lrow;                              \
            float e[4];                                                         \
            _Pragma("unroll")                                                   \
            for (int r = 0; r < 4; ++r) {                                       \
                int q = qb + quad * 4 + r;                                      \
                int ql = q & 63;                                                \
                int rel = min(max(key - q, -128), 128) + 128;                   \
                float p = bf2f(Qpos_l[ql][rel]);                                \
                e[r] = exp2_raw(__builtin_fmaf(s[j][r], CS, p));                \
            }                                                                   \
            const uint32_t p01 = cvt_pk_bf16(e[0], e[1]);                       \
            const uint32_t p23 = cvt_pk_bf16(e[2], e[3]);                       \
            const int col = j * 16 + lrow;                                      \
            const int rw = quad * 4;                                            \
            Pl[wave][rw + 0][col] = (uint16_t)p01;                              \
            Pl[wave][rw + 1][col] = (uint16_t)(p01 >> 16);                      \
            Pl[wave][rw + 2][col] = (uint16_t)p23;                              \
            Pl[wave][rw + 3][col] = (uint16_t)(p23 >> 16);                      \
        }                                                                       \
    }                                                                           \
    ap0 = *(const short8*)(&Pl[wave][lrow][quad * 8]);                          \
    ap1 = *(const short8*)(&Pl[wave][lrow][32 + quad * 8]);                     \
}

#define FA_BODY(TI, KC, KN, MC, MN)                                             \
{                                                                               \
    const int kb = (TI) * 64;                                                   \
    /* V(t) frags: 8 coalesced 1KB loads, consumed after SM */                  \
    const uint16_t* vb = Vp + (size_t)(TI) * 4096;                              \
    short8 vv[8];                                                               \
    _Pragma("unroll")                                                           \
    for (int sl = 0; sl < 8; ++sl)                                              \
        vv[sl] = *(const short8*)(vb + sl * 512 + lane8);                       \
    /* prefetch K(t+1) + mask(t+1) */                                           \
    const int tn = ((TI) + 1) & 15;                                             \
    const uint16_t* kbn = Kp + (size_t)tn * 4096;                               \
    _Pragma("unroll")                                                           \
    for (int sl = 0; sl < 8; ++sl)                                              \
        KN[sl] = *(const short8*)(kbn + sl * 512 + lane8);                      \
    MN[0] = *(const short8*)(mkb + tn * 64 + quad * 8);                         \
    MN[1] = *(const short8*)(mkb + tn * 64 + 32 + quad * 8);                    \
    f32x4 s[4];                                                                 \
    __builtin_amdgcn_s_setprio(1);                                              \
    _Pragma("unroll")                                                           \
    for (int j = 0; j < 4; ++j) {                                               \
        s[j] = __builtin_amdgcn_mfma_f32_16x16x32_bf16(aq0, KC[j * 2 + 0], fz, 0, 0, 0); \
        s[j] = __builtin_amdgcn_mfma_f32_16x16x32_bf16(aq1, KC[j * 2 + 1], s[j], 0, 0, 0); \
    }                                                                           \
    __builtin_amdgcn_s_setprio(0);                                              \
    FA_SM(kb)                                                                   \
    __builtin_amdgcn_s_setprio(1);                                              \
    _Pragma("unroll")                                                           \
    for (int dt = 0; dt < 4; ++dt) {                                            \
        o[dt] = __builtin_amdgcn_mfma_f32_16x16x32_bf16(ap0, vv[dt * 2 + 0], o[dt], 0, 0, 0); \
        o[dt] = __builtin_amdgcn_mfma_f32_16x16x32_bf16(ap1, vv[dt * 2 + 1], o[dt], 0, 0, 0); \
    }                                                                           \
    lacc = __builtin_amdgcn_mfma_f32_16x16x32_bf16(ap0, MC[0], lacc, 0, 0, 0);  \
    lacc = __builtin_amdgcn_mfma_f32_16x16x32_bf16(ap1, MC[1], lacc, 0, 0, 0);  \
    __builtin_amdgcn_s_setprio(0);                                              \
}

__global__ __launch_bounds__(256) void flash_attn(
    const uint16_t* __restrict__ Qh, const uint16_t* __restrict__ Kh,
    const uint16_t* __restrict__ Vt, const uint16_t* __restrict__ pos,
    const uint16_t* __restrict__ maskv, uint16_t* __restrict__ comb)
{
    const int blk = blockIdx.x;     // 0..1023
    const int jj = blk >> 3;        // 0..127
    const int bh = (blk & 7) * 8 + (jj >> 4);   // XCD-locality swizzle
    const int qt = jj & 15;
    const int b = bh >> 4;
    const int h = bh & 15;
    const int t = threadIdx.x;
    const int lane = t & 63;
    const int wave = t >> 6;
    const int lrow = lane & 15;
    const int quad = lane >> 4;
    const int qb = qt * 64 + wave * 16;
    const int lane8 = lane * 8;

    __shared__ alignas(16) uint16_t Qpos_l[64][277];   // 35456 B, wave-private rows
    __shared__ alignas(16) uint16_t Pl[4][16][72];     // 9216 B, wave-private

    const uint16_t* Kp = Kh + (size_t)bh * 65536;   // frag-native layout
    const uint16_t* Vp = Vt + (size_t)bh * 65536;   // frag-native layout
    const uint16_t* mkb = maskv + (size_t)b * 1024;

    const float CS = 0.18033688011f;   // 0.125 * log2(e)

    // issue tile-0 K + mask loads first: latency hides under the slab prologue
    short8 ka[8], kn[8], ma[2], mn[2];
#pragma unroll
    for (int sl = 0; sl < 8; ++sl)
        ka[sl] = *(const short8*)(Kp + sl * 512 + lane8);
    ma[0] = *(const short8*)(mkb + quad * 8);
    ma[1] = *(const short8*)(mkb + 32 + quad * 8);

    const uint16_t* Qp = Qh + ((size_t)bh * 1024 + qb) * 64;
    short8 aq0 = *(const short8*)(Qp + (size_t)lrow * 64 + quad * 8);
    short8 aq1 = *(const short8*)(Qp + (size_t)lrow * 64 + 32 + quad * 8);

    const f32x4 fz = {0.f, 0.f, 0.f, 0.f};

    // ---- prologue: 16x272 pos-logit slab (pre-scaled by CS), B-frags from
    // global (L2-hot). cvt_pk packs pairs; each wave writes only its 16 rows.
#pragma unroll 4
    for (int nt = 0; nt < 17; ++nt) {
        short8 pb0 = *(const short8*)(pos + (size_t)(nt * 16 + lrow) * 64 + quad * 8);
        short8 pb1 = *(const short8*)(pos + (size_t)(nt * 16 + lrow) * 64 + 32 + quad * 8);
        f32x4 c = __builtin_amdgcn_mfma_f32_16x16x32_bf16(aq0, pb0, fz, 0, 0, 0);
        c = __builtin_amdgcn_mfma_f32_16x16x32_bf16(aq1, pb1, c, 0, 0, 0);
        const uint32_t p01 = cvt_pk_bf16(c[0] * CS, c[1] * CS);
        const uint32_t p23 = cvt_pk_bf16(c[2] * CS, c[3] * CS);
        const int row = wave * 16 + quad * 4;
        const int col = nt * 16 + lrow;
        Qpos_l[row + 0][col] = (uint16_t)p01;
        Qpos_l[row + 1][col] = (uint16_t)(p01 >> 16);
        Qpos_l[row + 2][col] = (uint16_t)p23;
        Qpos_l[row + 3][col] = (uint16_t)(p23 >> 16);
    }

    float pcl[4], pch[4];
#pragma unroll
    for (int r = 0; r < 4; ++r) {
        int ql = wave * 16 + quad * 4 + r;
        pcl[r] = bf2f(Qpos_l[ql][0]);      // already * CS
        pch[r] = bf2f(Qpos_l[ql][256]);
    }

    f32x4 o[4] = {fz, fz, fz, fz};
    f32x4 lacc = fz;   // denominator accumulator (every lane: full row sum)
    short8 ap0, ap1;

    for (int t2 = 0; t2 < 16; t2 += 2) {
        FA_BODY(t2, ka, kn, ma, mn)
        FA_BODY(t2 + 1, kn, ka, mn, ma)
    }

    float inv[4];
#pragma unroll
    for (int r = 0; r < 4; ++r) inv[r] = 1.0f / lacc[r];

#pragma unroll
    for (int dt = 0; dt < 4; ++dt)
#pragma unroll
        for (int r = 0; r < 4; ++r) {
            size_t row = (size_t)b * 1024 + qb + quad * 4 + r;
            size_t col = (size_t)h * 64 + dt * 16 + lrow;
            comb[row * 1024 + col] = f2bf(o[dt][r] * inv[r]);
        }
}

// ---------------------------------------------------------------------------
// ws layout (~56.2 MB; ws_size >= ~72 MB evidenced rounds 0-3):
// Qh 8 | Khd 8 | Vt 8 | xqb 8 (comb reuse) | xkb 8 | xvb 8 | W*4 8 | posb |
// mbits | mvals
// ---------------------------------------------------------------------------
extern "C" void kernel_launch(void* const* d_in, const int* in_sizes, int n_in,
                              void* d_out, int out_size, void* d_ws, size_t ws_size,
                              hipStream_t stream)
{
    const float* x_q = (const float*)d_in[0];
    const float* x_k = (const float*)d_in[1];
    const float* x_v = (const float*)d_in[2];
    const void*  msk = d_in[3];
    const float* Wq  = (const float*)d_in[4];
    const float* Wk  = (const float*)d_in[5];
    const float* Wv  = (const float*)d_in[6];
    const float* Wo  = (const float*)d_in[7];
    const float* pos = (const float*)d_in[8];

    char* ws = (char*)d_ws;
    const size_t MB = 1u << 20;
    uint16_t* Qh   = (uint16_t*)(ws);
    uint16_t* Khd  = (uint16_t*)(ws + 8 * MB);
    uint16_t* Vt   = (uint16_t*)(ws + 16 * MB);
    uint16_t* xqb  = (uint16_t*)(ws + 24 * MB);
    uint16_t* xkb  = (uint16_t*)(ws + 32 * MB);
    uint16_t* xvb  = (uint16_t*)(ws + 40 * MB);
    uint16_t* Wqb  = (uint16_t*)(ws + 48 * MB);
    uint16_t* Wkb  = (uint16_t*)(ws + 50 * MB);
    uint16_t* Wvb  = (uint16_t*)(ws + 52 * MB);
    uint16_t* Wob  = (uint16_t*)(ws + 54 * MB);
    uint16_t* posb = (uint16_t*)(ws + 56 * MB);       // 272x64 bf16, rows 257+ zero
    unsigned long long* mbits = (unsigned long long*)(ws + 56 * MB + 65536);
    uint16_t* mvals = (uint16_t*)(ws + 56 * MB + 65536 + 4096);  // 4x1024 bf16
    uint16_t* comb = xqb;  // xqb dead after projections; flash runs after them

    CvtArgs ca{};
    int ns = 0;
    ca.seg[ns++] = {x_q, xqb, 524288};
    ca.seg[ns++] = {x_k, xkb, 524288};
    ca.seg[ns++] = {x_v, xvb, 524288};
    ca.seg[ns++] = {Wq, Wqb, 131072};
    ca.seg[ns++] = {Wk, Wkb, 131072};
    ca.seg[ns++] = {Wv, Wvb, 131072};
    ca.seg[ns++] = {Wo, Wob, 131072};
    ca.seg[ns++] = {pos, posb, 2056};              // 257*64/8
    ca.seg[ns++] = {nullptr, posb + 16448, 120};   // zero rows 257..271
    ca.nseg = ns;
    ca.mraw = msk;
    ca.mbits = mbits;
    ca.mvals = mvals;
    cvt_bf16<<<dim3(512), dim3(256), 0, stream>>>(ca);

    // Fused Q/K/V projections, BK=64 two-half staging: 32x8x3 = 768 blocks
    gemm128_qkv<<<dim3(32, 8, 3), dim3(256), 0, stream>>>(
        xqb, xkb, xvb, Wqb, Wkb, Wvb, Qh, Khd, Vt, mbits);

    flash_attn<<<dim3(1024), dim3(256), 0, stream>>>(Qh, Khd, Vt, posb, mvals, comb);

    // Output projection: comb(bf16) @ Wo_b^T -> fp32 d_out (64x128, BK=64)
    gemm_out<<<dim3(64, 8), dim3(256), 0, stream>>>(
        comb, Wob, (float*)d_out, 4096, 1024, 1024);
}

// Round 8
// 224.128 us; speedup vs baseline: 1.0955x; 1.0955x over previous
//
#include <hip/hip_runtime.h>
#include <hip/hip_bf16.h>
#include <stdint.h>

typedef __attribute__((ext_vector_type(8))) short short8;  // 8 bf16 (4 VGPRs)
typedef __attribute__((ext_vector_type(4))) float f32x4;   // 4 fp32 acc

__device__ __forceinline__ uint16_t f2bf(float f) {
    union { float f; uint32_t u; } v; v.f = f;
    uint32_t r = v.u + 0x7FFF + ((v.u >> 16) & 1);  // RNE
    return (uint16_t)(r >> 16);
}
__device__ __forceinline__ float bf2f(uint16_t u) {
    union { uint32_t u; float f; } v; v.u = ((uint32_t)u) << 16;
    return v.f;
}
__device__ __forceinline__ float exp2_raw(float x) {
    float r;
    asm("v_exp_f32 %0, %1" : "=v"(r) : "v"(x));
    return r;
}
__device__ __forceinline__ uint32_t cvt_pk_bf16(float lo, float hi) {
    uint32_t r;
    asm("v_cvt_pk_bf16_f32 %0, %1, %2" : "=v"(r) : "v"(lo), "v"(hi));
    return r;
}

template<int F32>
__device__ __forceinline__ uint4 load8(const void* p, size_t off) {
    if (F32) {
        const float* f = (const float*)p + off;
        float4 f0 = *(const float4*)f;
        float4 f1 = *(const float4*)(f + 4);
        uint4 r;
        r.x = (uint32_t)f2bf(f0.x) | ((uint32_t)f2bf(f0.y) << 16);
        r.y = (uint32_t)f2bf(f0.z) | ((uint32_t)f2bf(f0.w) << 16);
        r.z = (uint32_t)f2bf(f1.x) | ((uint32_t)f2bf(f1.y) << 16);
        r.w = (uint32_t)f2bf(f1.z) | ((uint32_t)f2bf(f1.w) << 16);
        return r;
    } else {
        return *(const uint4*)((const uint16_t*)p + off);
    }
}

// global -> LDS direct DMA, 16 B/lane; LDS dest = wave-uniform base + lane*16.
#define GLDS(gp, lp) __builtin_amdgcn_global_load_lds( \
    (const __attribute__((address_space(1))) void*)(gp), \
    (__attribute__((address_space(3))) void*)(lp), 16, 0, 0)

// ---------------------------------------------------------------------------
// cvt (x + weights + pos) + mask canonicalization fused. Mask products:
//  * mbits: 1024-bit-per-batch bitmask (used by gemm128_qkv V-epilogue)
//  * mvals: bf16 {1.0 unmasked, 0.0 masked} per (b,k) — flash_attn's
//    denominator B-fragment (lsum via MFMA instead of 64 VALU adds/iter).
// ---------------------------------------------------------------------------
struct CvtSeg { const float* s; uint16_t* d; int n8; };
struct CvtArgs {
    CvtSeg seg[9]; int nseg;
    const void* mraw; unsigned long long* mbits; uint16_t* mvals;
};

__global__ __launch_bounds__(256) void cvt_bf16(CvtArgs a)
{
    if (blockIdx.x == 0) {
        __shared__ int flags[3];
        __shared__ uint8_t mloc[4096];
        const uint32_t* w = (const uint32_t*)a.mraw;
        const uint8_t* b8 = (const uint8_t*)a.mraw;
        const int t = threadIdx.x;
        if (t < 3) flags[t] = 0;
        __syncthreads();
        int fbyte = 0, ff32 = 0, fodd = 0;
        for (int i = t; i < 1024; i += 256) {
            uint32_t v = w[i];
            if (v != 0u && v != 1u && v != 0x3F800000u) fbyte = 1;
            if (v == 0x3F800000u) ff32 = 1;
            if ((i & 1) && v != 0u) fodd = 1;
        }
        if (fbyte) atomicOr(&flags[0], 1);
        if (ff32)  atomicOr(&flags[1], 1);
        if (fodd)  atomicOr(&flags[2], 1);
        __syncthreads();
        int mode;  // 0 = word, 1 = byte, 2 = int64
        if (flags[0]) mode = 1;
        else if (flags[1]) mode = 0;
        else if (!flags[2]) mode = 2;
        else mode = 0;
        for (int k = t; k < 4096; k += 256) {
            int val;
            if (mode == 1)      val = (b8[k] != 0);
            else if (mode == 2) val = (w[2 * k] != 0u);
            else                val = (w[k] != 0u);
            mloc[k] = (uint8_t)val;
        }
        __syncthreads();
        for (int k = t; k < 4096; k += 256)
            a.mvals[k] = mloc[k] ? (uint16_t)0 : (uint16_t)0x3F80;
        if (t < 64) {
            uint64_t bits = 0;
#pragma unroll
            for (int i = 0; i < 64; ++i)
                bits |= (uint64_t)mloc[t * 64 + i] << i;
            a.mbits[t] = bits;
        }
    }
    const int tid = blockIdx.x * 256 + threadIdx.x;
    const int stride = gridDim.x * 256;
    for (int s = 0; s < a.nseg; ++s) {
        const float* src = a.seg[s].s;
        uint16_t* dst = a.seg[s].d;
        const int n8 = a.seg[s].n8;
        if (src) {
            for (int i = tid; i < n8; i += stride)
                *(uint4*)(dst + (size_t)i * 8) = load8<1>(src, (size_t)i * 8);
        } else {
            const uint4 z = {0u, 0u, 0u, 0u};
            for (int i = tid; i < n8; i += stride)
                *(uint4*)(dst + (size_t)i * 8) = z;
        }
    }
}

// ---------------------------------------------------------------------------
// QKV GEMM, 128x128 tile, BK=64 — r13-proven main loop, untouched.
// Outputs (r8):
//   Q: row-major [bh][t][d]                      (r5 form)
//   K: row-major [bh][key][d]                    (r5 form — GLDS staging
//      consumes rows; r7's K frag store scattered 2B writes, cost ~12us)
//   V: FRAG-NATIVE [bh][tile][slot][lane*8]      (r7-proven: slot=512 u16,
//      tile=4096 u16) so flash V loads are coalesced lane*16B transactions.
// V epilogue zeroes masked key columns (wave-uniform s_load of mbits, r5).
// ---------------------------------------------------------------------------
__global__ __launch_bounds__(256) void gemm128_qkv(
    const uint16_t* __restrict__ xq, const uint16_t* __restrict__ xk, const uint16_t* __restrict__ xv,
    const uint16_t* __restrict__ Wq, const uint16_t* __restrict__ Wk, const uint16_t* __restrict__ Wv,
    uint16_t* __restrict__ Qh, uint16_t* __restrict__ Khd, uint16_t* __restrict__ Vt,
    const unsigned long long* __restrict__ mbits)
{
    __shared__ alignas(16) uint16_t As[2][128 * 32];   // k-halves
    __shared__ alignas(16) uint16_t Bs[2][128 * 32];

    const int z = blockIdx.z;
    const uint16_t* A = (z == 0) ? xq : (z == 1) ? xk : xv;
    const uint16_t* B = (z == 0) ? Wq : (z == 1) ? Wk : Wv;
    uint16_t* C = (z == 0) ? Qh : (z == 1) ? Khd : Vt;
    const int cm = (z == 2) ? 2 : 1;
    const int bm = blockIdx.x, bn = blockIdx.y;
    const int K = 1024;

    const int t = threadIdx.x;
    const int lane = t & 63, wave = t >> 6;
    const int lrow = lane & 15, quad = lane >> 4;
    const int wr = (wave >> 1) * 64, wc = (wave & 1) * 64;
    const int g_row = wave * 16 + (lane >> 2);
    const int g_col = (lane & 3) * 8;

    const f32x4 fz = {0.f, 0.f, 0.f, 0.f};
    f32x4 acc[4][4];
#pragma unroll
    for (int i = 0; i < 4; ++i)
#pragma unroll
        for (int j = 0; j < 4; ++j) acc[i][j] = fz;

    for (int k0 = 0; k0 < K; k0 += 64) {
        __syncthreads();
#pragma unroll
        for (int kh = 0; kh < 2; ++kh) {
            const int kk = k0 + kh * 32;
            GLDS(A + (size_t)(bm * 128 + g_row) * K + kk + g_col,      As[kh] + wave * 512);
            GLDS(A + (size_t)(bm * 128 + g_row + 64) * K + kk + g_col, As[kh] + wave * 512 + 2048);
            GLDS(B + (size_t)(bn * 128 + g_row) * K + kk + g_col,      Bs[kh] + wave * 512);
            GLDS(B + (size_t)(bn * 128 + g_row + 64) * K + kk + g_col, Bs[kh] + wave * 512 + 2048);
        }
        __syncthreads();

#pragma unroll
        for (int kh = 0; kh < 2; ++kh) {
            short8 a[4], b[4];
#pragma unroll
            for (int i = 0; i < 4; ++i)
                a[i] = *(const short8*)(As[kh] + (wr + i * 16 + lrow) * 32 + quad * 8);
#pragma unroll
            for (int j = 0; j < 4; ++j)
                b[j] = *(const short8*)(Bs[kh] + (wc + j * 16 + lrow) * 32 + quad * 8);
#pragma unroll
            for (int i = 0; i < 4; ++i)
#pragma unroll
                for (int j = 0; j < 4; ++j)
                    acc[i][j] = __builtin_amdgcn_mfma_f32_16x16x32_bf16(a[i], b[j], acc[i][j], 0, 0, 0);
        }
    }

    if (cm == 2) {
        __syncthreads();
        uint16_t* scr = As[0] + wave * 1024;
        // wave-uniform mask word (r5-proven): one s_load, VALU-extract.
        const int mg0 = bm * 128 + wr;
        const int widx = __builtin_amdgcn_readfirstlane((mg0 >> 10) * 16 + ((mg0 & 1023) >> 6));
        const uint64_t mword = mbits[widx];
        const uint64_t mw64 = mword >> ((lane & 1) * 8);
#pragma unroll
        for (int i = 0; i < 4; ++i)
#pragma unroll
            for (int j = 0; j < 4; ++j) {
                uint2 pk;
                pk.x = (uint32_t)f2bf(acc[i][j][0]) | ((uint32_t)f2bf(acc[i][j][1]) << 16);
                pk.y = (uint32_t)f2bf(acc[i][j][2]) | ((uint32_t)f2bf(acc[i][j][3]) << 16);
                *(uint2*)(scr + lrow * 16 + quad * 4) = pk;
                if (lane < 32) {
                    int n = lane >> 1, m8 = (lane & 1) * 8;
                    short8 vv = *(const short8*)(scr + n * 16 + m8);
                    int ng = bn * 128 + wc + j * 16 + n;        // (h,d)
                    int hh = ng >> 6, d = ng & 63;
                    int mg = bm * 128 + wr + i * 16;            // t base
                    int bb = mg >> 10, tl = (mg & 1023) + m8;   // key base (8-aligned)
                    uint32_t eb = (uint32_t)(mw64 >> (i * 16)) & 0xFFu;
                    if (eb) {
                        union { short8 s; uint32_t u[4]; } uw;
                        uw.s = vv;
#pragma unroll
                        for (int c = 0; c < 4; ++c) {
                            uint32_t km = (((eb >> (2 * c)) & 1) ? 0u : 0x0000FFFFu)
                                        | (((eb >> (2 * c + 1)) & 1) ? 0u : 0xFFFF0000u);
                            uw.u[c] &= km;
                        }
                        vv = uw.s;
                    }
                    // V frag-native addr (r7-proven; keys tl..tl+7: e = key&7)
                    size_t addr = (size_t)(bb * 16 + hh) * 65536
                                + (size_t)((tl >> 6) * 4096
                                           + ((d >> 4) * 2 + ((tl >> 5) & 1)) * 512
                                           + ((tl >> 3) & 3) * 128 + (d & 15) * 8);
                    *(short8*)(C + addr) = vv;
                }
            }
        return;
    }

#pragma unroll
    for (int i = 0; i < 4; ++i)
#pragma unroll
        for (int j = 0; j < 4; ++j)
#pragma unroll
            for (int r = 0; r < 4; ++r) {
                // verified C/D map: row = quad*4 + reg, col = lane&15
                int m = bm * 128 + wr + i * 16 + quad * 4 + r;
                int n = bn * 128 + wc + j * 16 + lrow;
                int bb = m >> 10, tt = m & 1023, hh = n >> 6, d = n & 63;
                C[(((size_t)bb * 16 + hh) * 1024 + tt) * 64 + d] = f2bf(acc[i][j][r]);
            }
}

// ---------------------------------------------------------------------------
// Output projection, 64x128 tiles (512 blocks = 2/CU), BK=64 — exact r13
// version. 16 MFMA/iter. LDS 24KB.
// ---------------------------------------------------------------------------
__global__ __launch_bounds__(256) void gemm_out(
    const uint16_t* __restrict__ A, const uint16_t* __restrict__ B,
    float* __restrict__ C, int M, int N, int K)
{
    __shared__ alignas(16) uint16_t As[2][64 * 32];
    __shared__ alignas(16) uint16_t Bs[2][128 * 32];

    const int t = threadIdx.x;
    const int lane = t & 63, wave = t >> 6;
    const int lrow = lane & 15, quad = lane >> 4;
    const int wr = (wave >> 1) * 32, wc = (wave & 1) * 64;
    const int g_row = wave * 16 + (lane >> 2);
    const int g_col = (lane & 3) * 8;
    const int bm = blockIdx.x, bn = blockIdx.y;

    const f32x4 fz = {0.f, 0.f, 0.f, 0.f};
    f32x4 acc[2][4];
#pragma unroll
    for (int i = 0; i < 2; ++i)
#pragma unroll
        for (int j = 0; j < 4; ++j) acc[i][j] = fz;

    for (int k0 = 0; k0 < K; k0 += 64) {
        __syncthreads();
#pragma unroll
        for (int kh = 0; kh < 2; ++kh) {
            const int kk = k0 + kh * 32;
            GLDS(A + (size_t)(bm * 64 + g_row) * K + kk + g_col,       As[kh] + wave * 512);
            GLDS(B + (size_t)(bn * 128 + g_row) * K + kk + g_col,      Bs[kh] + wave * 512);
            GLDS(B + (size_t)(bn * 128 + g_row + 64) * K + kk + g_col, Bs[kh] + wave * 512 + 2048);
        }
        __syncthreads();

#pragma unroll
        for (int kh = 0; kh < 2; ++kh) {
            short8 a[2], b[4];
#pragma unroll
            for (int i = 0; i < 2; ++i)
                a[i] = *(const short8*)(As[kh] + (wr + i * 16 + lrow) * 32 + quad * 8);
#pragma unroll
            for (int j = 0; j < 4; ++j)
                b[j] = *(const short8*)(Bs[kh] + (wc + j * 16 + lrow) * 32 + quad * 8);
#pragma unroll
            for (int i = 0; i < 2; ++i)
#pragma unroll
                for (int j = 0; j < 4; ++j)
                    acc[i][j] = __builtin_amdgcn_mfma_f32_16x16x32_bf16(a[i], b[j], acc[i][j], 0, 0, 0);
        }
    }

#pragma unroll
    for (int i = 0; i < 2; ++i)
#pragma unroll
        for (int j = 0; j < 4; ++j)
#pragma unroll
            for (int r = 0; r < 4; ++r) {
                int m = bm * 64 + wr + i * 16 + quad * 4 + r;
                int n = bn * 128 + wc + j * 16 + lrow;
                C[(size_t)m * N + n] = acc[i][j][r];
            }
}

// ---------------------------------------------------------------------------
// Flash attention v14 — hybrid occupancy play:
//  * K keeps GLDS staging (r3/r7 lesson: LDS round-trip IS the latency
//    hiding for the critical operand) but SINGLE-buffered: per iter —
//    B1 (K(t) DMA done) -> ds_read K(t) into regs -> B2 (pure sync; all
//    waves' reads done) -> GLDS K(t+1) into the same buffer. The DMA has
//    SM+PV+next-B1 to land.
//  * V via DIRECT global loads from the r7-proven frag-native layout
//    (8x coalesced 1KB; issued before QK, consumed after SM). V is the
//    non-critical operand — the half of r7 that worked.
//  * Vs (16KB) + maskl (2KB) deleted; mask B-frags read from L2.
//  * LDS 79.9K -> 52864 B -> 3 blocks/CU (158.6KB < 160KiB).
//    __launch_bounds__(256,3) pins VGPR <= 170 for 3 waves/SIMD.
// Kept: mask-free SM (V pre-zeroed), MFMA denominator lacc, exp2+CS,
// cvt_pk packing, Qpos width 277, K chunk swizzle, setprio clusters.
// ---------------------------------------------------------------------------
#define FA_SM(KB_)                                                              \
{                                                                               \
    const int diff = (KB_) - qb;                                                \
    if (diff <= -192 || diff >= 144) {                                          \
        const bool low = (diff <= -192);                                        \
        _Pragma("unroll")                                                       \
        for (int j = 0; j < 4; ++j) {                                           \
            float e[4];                                                         \
            _Pragma("unroll")                                                   \
            for (int r = 0; r < 4; ++r) {                                       \
                float pc = low ? pcl[r] : pch[r];                               \
                e[r] = exp2_raw(__builtin_fmaf(s[j][r], CS, pc));               \
            }                                                                   \
            const uint32_t p01 = cvt_pk_bf16(e[0], e[1]);                       \
            const uint32_t p23 = cvt_pk_bf16(e[2], e[3]);                       \
            const int col = j * 16 + lrow;                                      \
            const int rw = quad * 4;                                            \
            Pl[wave][rw + 0][col] = (uint16_t)p01;                              \
            Pl[wave][rw + 1][col] = (uint16_t)(p01 >> 16);                      \
            Pl[wave][rw + 2][col] = (uint16_t)p23;                              \
            Pl[wave][rw + 3][col] = (uint16_t)(p23 >> 16);                      \
        }                                                                       \
    } else {                                                                    \
        _Pragma("unroll")                                                       \
        for (int j = 0; j < 4; ++j) {                                           \
            const int key = (KB_) + j * 16 + lrow;                              \
            float e[4];                                                         \
            _Pragma("unroll")                                                   \
            for (int r = 0; r < 4; ++r) {                                       \
                int q = qb + quad * 4 + r;                                      \
                int ql = q & 63;                                                \
                int rel = min(max(key - q, -128), 128) + 128;                   \
                float p = bf2f(Qpos_l[ql][rel]);                                \
                e[r] = exp2_raw(__builtin_fmaf(s[j][r], CS, p));                \
            }                                                                   \
            const uint32_t p01 = cvt_pk_bf16(e[0], e[1]);                       \
            const uint32_t p23 = cvt_pk_bf16(e[2], e[3]);                       \
            const int col = j * 16 + lrow;                                      \
            const int rw = quad * 4;                                            \
            Pl[wave][rw + 0][col] = (uint16_t)p01;                              \
            Pl[wave][rw + 1][col] = (uint16_t)(p01 >> 16);                      \
            Pl[wave][rw + 2][col] = (uint16_t)p23;                              \
            Pl[wave][rw + 3][col] = (uint16_t)(p23 >> 16);                      \
        }                                                                       \
    }                                                                           \
    ap0 = *(const short8*)(&Pl[wave][lrow][quad * 8]);                          \
    ap1 = *(const short8*)(&Pl[wave][lrow][32 + quad * 8]);                     \
}

__global__ __launch_bounds__(256, 3) void flash_attn(
    const uint16_t* __restrict__ Qh, const uint16_t* __restrict__ Kh,
    const uint16_t* __restrict__ Vt, const uint16_t* __restrict__ pos,
    const uint16_t* __restrict__ maskv, uint16_t* __restrict__ comb)
{
    const int blk = blockIdx.x;     // 0..1023
    const int jj = blk >> 3;        // 0..127
    const int bh = (blk & 7) * 8 + (jj >> 4);   // XCD-locality swizzle
    const int qt = jj & 15;
    const int b = bh >> 4;
    const int h = bh & 15;
    const int t = threadIdx.x;
    const int lane = t & 63;
    const int wave = t >> 6;
    const int lrow = lane & 15;
    const int quad = lane >> 4;
    const int qb = qt * 64 + wave * 16;
    const int lane8 = lane * 8;

    __shared__ alignas(16) uint16_t Ks[4096];          // 8 KB, SINGLE buffer
    __shared__ alignas(16) uint16_t Qpos_l[64][277];   // 35456 B, bank-clean
    __shared__ alignas(16) uint16_t Pl[4][16][72];     // 9216 B, wave-private

    const uint16_t* Kp = Kh + (size_t)bh * 65536;   // row-major [key][d]
    const uint16_t* Vp = Vt + (size_t)bh * 65536;   // frag-native
    const uint16_t* mkb = maskv + (size_t)b * 1024;

    const int sg_r = lane >> 2;
    // pre-swizzled global source chunk (r5-proven): LDS stays linear for
    // GLDS; LDS chunk c of row r holds global chunk c^((r>>1)&3).
    const int sg_c = ((lane & 3) ^ ((sg_r >> 1) & 3)) * 8;
    const int hw = wave >> 1;
    const int gw = (wave & 1) * 2;
    const int rdc = (quad ^ ((lrow >> 1) & 3)) * 8;    // swizzled read chunk

    const float CS = 0.18033688011f;   // 0.125 * log2(e)

    // issue tile-0 K staging first: latency hides under the slab prologue
#pragma unroll
    for (int gg = 0; gg < 2; ++gg) {
        int g = gw + gg;
        GLDS(Kp + (size_t)(g * 16 + sg_r) * 64 + hw * 32 + sg_c, &Ks[hw * 2048 + g * 512]);
    }

    const uint16_t* Qp = Qh + ((size_t)bh * 1024 + qb) * 64;
    short8 aq0 = *(const short8*)(Qp + (size_t)lrow * 64 + quad * 8);
    short8 aq1 = *(const short8*)(Qp + (size_t)lrow * 64 + 32 + quad * 8);

    const f32x4 fz = {0.f, 0.f, 0.f, 0.f};

    // ---- prologue: 16x272 pos-logit slab (pre-scaled by CS), B-frags from
    // global (L2-hot). cvt_pk packs pairs; each wave writes only its 16 rows.
#pragma unroll 4
    for (int nt = 0; nt < 17; ++nt) {
        short8 pb0 = *(const short8*)(pos + (size_t)(nt * 16 + lrow) * 64 + quad * 8);
        short8 pb1 = *(const short8*)(pos + (size_t)(nt * 16 + lrow) * 64 + 32 + quad * 8);
        f32x4 c = __builtin_amdgcn_mfma_f32_16x16x32_bf16(aq0, pb0, fz, 0, 0, 0);
        c = __builtin_amdgcn_mfma_f32_16x16x32_bf16(aq1, pb1, c, 0, 0, 0);
        const uint32_t p01 = cvt_pk_bf16(c[0] * CS, c[1] * CS);
        const uint32_t p23 = cvt_pk_bf16(c[2] * CS, c[3] * CS);
        const int row = wave * 16 + quad * 4;
        const int col = nt * 16 + lrow;
        Qpos_l[row + 0][col] = (uint16_t)p01;
        Qpos_l[row + 1][col] = (uint16_t)(p01 >> 16);
        Qpos_l[row + 2][col] = (uint16_t)p23;
        Qpos_l[row + 3][col] = (uint16_t)(p23 >> 16);
    }

    float pcl[4], pch[4];
#pragma unroll
    for (int r = 0; r < 4; ++r) {
        int ql = wave * 16 + quad * 4 + r;
        pcl[r] = bf2f(Qpos_l[ql][0]);      // already * CS
        pch[r] = bf2f(Qpos_l[ql][256]);
    }

    f32x4 o[4] = {fz, fz, fz, fz};
    f32x4 lacc = fz;   // denominator accumulator (every lane: full row sum)
    short8 ap0, ap1;

    for (int ti = 0; ti < 16; ++ti) {
        const int kb = ti * 64;
        __syncthreads();               // B1: K(ti) DMA complete
        short8 kr[8];
#pragma unroll
        for (int j = 0; j < 4; ++j) {
            kr[j * 2 + 0] = *(const short8*)(Ks + (j * 16 + lrow) * 32 + rdc);
            kr[j * 2 + 1] = *(const short8*)(Ks + 2048 + (j * 16 + lrow) * 32 + rdc);
        }
        __syncthreads();               // B2: all waves' K reads done
        if (ti < 15) {
#pragma unroll
            for (int gg = 0; gg < 2; ++gg) {
                int g = gw + gg;
                GLDS(Kp + (size_t)(kb + 64 + g * 16 + sg_r) * 64 + hw * 32 + sg_c,
                     &Ks[hw * 2048 + g * 512]);
            }
        }
        // V(ti) + mask(ti): direct coalesced loads; consumed after SM
        const uint16_t* vb = Vp + (size_t)ti * 4096;
        short8 vv[8];
#pragma unroll
        for (int sl = 0; sl < 8; ++sl)
            vv[sl] = *(const short8*)(vb + sl * 512 + lane8);
        short8 bm0 = *(const short8*)(mkb + kb + quad * 8);
        short8 bm1 = *(const short8*)(mkb + kb + 32 + quad * 8);

        f32x4 s[4];
        __builtin_amdgcn_s_setprio(1);
#pragma unroll
        for (int j = 0; j < 4; ++j) {
            s[j] = __builtin_amdgcn_mfma_f32_16x16x32_bf16(aq0, kr[j * 2 + 0], fz, 0, 0, 0);
            s[j] = __builtin_amdgcn_mfma_f32_16x16x32_bf16(aq1, kr[j * 2 + 1], s[j], 0, 0, 0);
        }
        __builtin_amdgcn_s_setprio(0);

        FA_SM(kb)

        __builtin_amdgcn_s_setprio(1);
#pragma unroll
        for (int dt = 0; dt < 4; ++dt) {
            o[dt] = __builtin_amdgcn_mfma_f32_16x16x32_bf16(ap0, vv[dt * 2 + 0], o[dt], 0, 0, 0);
            o[dt] = __builtin_amdgcn_mfma_f32_16x16x32_bf16(ap1, vv[dt * 2 + 1], o[dt], 0, 0, 0);
        }
        lacc = __builtin_amdgcn_mfma_f32_16x16x32_bf16(ap0, bm0, lacc, 0, 0, 0);
        lacc = __builtin_amdgcn_mfma_f32_16x16x32_bf16(ap1, bm1, lacc, 0, 0, 0);
        __builtin_amdgcn_s_setprio(0);
    }

    float inv[4];
#pragma unroll
    for (int r = 0; r < 4; ++r) inv[r] = 1.0f / lacc[r];

#pragma unroll
    for (int dt = 0; dt < 4; ++dt)
#pragma unroll
        for (int r = 0; r < 4; ++r) {
            size_t row = (size_t)b * 1024 + qb + quad * 4 + r;
            size_t col = (size_t)h * 64 + dt * 16 + lrow;
            comb[row * 1024 + col] = f2bf(o[dt][r] * inv[r]);
        }
}

// ---------------------------------------------------------------------------
// ws layout (~56.2 MB; ws_size >= ~72 MB evidenced rounds 0-3):
// Qh 8 | Khd 8 | Vt 8 | xqb 8 (comb reuse) | xkb 8 | xvb 8 | W*4 8 | posb |
// mbits | mvals
// ---------------------------------------------------------------------------
extern "C" void kernel_launch(void* const* d_in, const int* in_sizes, int n_in,
                              void* d_out, int out_size, void* d_ws, size_t ws_size,
                              hipStream_t stream)
{
    const float* x_q = (const float*)d_in[0];
    const float* x_k = (const float*)d_in[1];
    const float* x_v = (const float*)d_in[2];
    const void*  msk = d_in[3];
    const float* Wq  = (const float*)d_in[4];
    const float* Wk  = (const float*)d_in[5];
    const float* Wv  = (const float*)d_in[6];
    const float* Wo  = (const float*)d_in[7];
    const float* pos = (const float*)d_in[8];

    char* ws = (char*)d_ws;
    const size_t MB = 1u << 20;
    uint16_t* Qh   = (uint16_t*)(ws);
    uint16_t* Khd  = (uint16_t*)(ws + 8 * MB);
    uint16_t* Vt   = (uint16_t*)(ws + 16 * MB);
    uint16_t* xqb  = (uint16_t*)(ws + 24 * MB);
    uint16_t* xkb  = (uint16_t*)(ws + 32 * MB);
    uint16_t* xvb  = (uint16_t*)(ws + 40 * MB);
    uint16_t* Wqb  = (uint16_t*)(ws + 48 * MB);
    uint16_t* Wkb  = (uint16_t*)(ws + 50 * MB);
    uint16_t* Wvb  = (uint16_t*)(ws + 52 * MB);
    uint16_t* Wob  = (uint16_t*)(ws + 54 * MB);
    uint16_t* posb = (uint16_t*)(ws + 56 * MB);       // 272x64 bf16, rows 257+ zero
    unsigned long long* mbits = (unsigned long long*)(ws + 56 * MB + 65536);
    uint16_t* mvals = (uint16_t*)(ws + 56 * MB + 65536 + 4096);  // 4x1024 bf16
    uint16_t* comb = xqb;  // xqb dead after projections; flash runs after them

    CvtArgs ca{};
    int ns = 0;
    ca.seg[ns++] = {x_q, xqb, 524288};
    ca.seg[ns++] = {x_k, xkb, 524288};
    ca.seg[ns++] = {x_v, xvb, 524288};
    ca.seg[ns++] = {Wq, Wqb, 131072};
    ca.seg[ns++] = {Wk, Wkb, 131072};
    ca.seg[ns++] = {Wv, Wvb, 131072};
    ca.seg[ns++] = {Wo, Wob, 131072};
    ca.seg[ns++] = {pos, posb, 2056};              // 257*64/8
    ca.seg[ns++] = {nullptr, posb + 16448, 120};   // zero rows 257..271
    ca.nseg = ns;
    ca.mraw = msk;
    ca.mbits = mbits;
    ca.mvals = mvals;
    cvt_bf16<<<dim3(512), dim3(256), 0, stream>>>(ca);

    // Fused Q/K/V projections, BK=64 two-half staging: 32x8x3 = 768 blocks
    gemm128_qkv<<<dim3(32, 8, 3), dim3(256), 0, stream>>>(
        xqb, xkb, xvb, Wqb, Wkb, Wvb, Qh, Khd, Vt, mbits);

    flash_attn<<<dim3(1024), dim3(256), 0, stream>>>(Qh, Khd, Vt, posb, mvals, comb);

    // Output projection: comb(bf16) @ Wo_b^T -> fp32 d_out (64x128, BK=64)
    gemm_out<<<dim3(64, 8), dim3(256), 0, stream>>>(
        comb, Wob, (float*)d_out, 4096, 1024, 1024);
}